// Round 7
// baseline (249.532 us; speedup 1.0000x reference)
//
#include <hip/hip_runtime.h>

// MultiHeadSelfAttention  B=2 S=2048 D=1024 H=16 d=64, fp32 in/out.
// R6: fusion. 7 launches -> 4; qkv intermediate buffer eliminated.
//   prep: x->fp16, W_qkv -> transposed fp16 with SECTION-MAJOR column permute
//         (col' = sec*1024 + h*64 + d), W_out -> transposed fp16.
//   gemm_qkv: m97-structure fp16 MFMA GEMM whose epilogue writes directly:
//         sec0 -> Qh[t][h*64+d], pre-scaled by log2(e)/8 (after bias)
//         sec1 -> Ksw[b,h][d/8][s][8]   sec2 -> Vsw[b,h][s/8][d][8]
//         (sec is block-uniform since 1024 % 128 == 0)
//   attn: R5 kernel, Q from Qh (already scaled), K/V staging = contiguous 1KB
//         global_load_lds; max-free exp2 softmax; S^T tiles.
//   gemm_out: fp16 MFMA GEMM -> fp32 out.
// ws: Qh 8M @0 | Ksw 8M @8M | Vsw 8M @16M | val_h 8M @24M | wq_t 6M @32M
//     | wo_t 2M @38M | x_h 8M @40M   (48 MiB total)

#define D_MODEL 1024
#define NHEAD   16
#define HDIM    64
#define SEQ     2048
#define BATCH   2
#define NTOK    (BATCH * SEQ)

typedef float    f32x4 __attribute__((ext_vector_type(4)));
typedef _Float16 f16x8 __attribute__((ext_vector_type(8)));
typedef _Float16 f16x4 __attribute__((ext_vector_type(4)));

#define GLOBAL_LOAD_LDS16(gptr, lptr)                                            \
    __builtin_amdgcn_global_load_lds(                                            \
        (const __attribute__((address_space(1))) unsigned int*)(gptr),           \
        (__attribute__((address_space(3))) unsigned int*)(lptr), 16, 0, 0)

// ---------------- prep: convert x, transpose(+permute) weights ----------------
// blocks [0,4096): x fp32->fp16 (4 elem/thread)
// blocks [4096,4864): W_qkv 64x64 transpose tiles, column-permuted
// blocks [4864,5120): W_out 64x64 transpose tiles
__global__ __launch_bounds__(256) void prep_kernel(
    const float* __restrict__ x, _Float16* __restrict__ xh,
    const float* __restrict__ Wqkv, _Float16* __restrict__ wq_t,
    const float* __restrict__ Wout, _Float16* __restrict__ wo_t)
{
    const int bx = blockIdx.x;
    const int tid = threadIdx.x;
    if (bx < 4096) {
        const int i = (bx * 256 + tid) * 4;
        const float4 v = *(const float4*)&x[i];
        f16x4 hh;
        hh[0] = (_Float16)v.x; hh[1] = (_Float16)v.y;
        hh[2] = (_Float16)v.z; hh[3] = (_Float16)v.w;
        *(f16x4*)&xh[i] = hh;
        return;
    }
    __shared__ float ts[64][65];
    const float* W; _Float16* Wt; int N, n0, k0; bool perm;
    if (bx < 4096 + 768) {
        const int local = bx - 4096;
        W = Wqkv; Wt = wq_t; N = 3072;
        n0 = (local % 48) * 64; k0 = (local / 48) * 64; perm = true;
    } else {
        const int local = bx - 4864;
        W = Wout; Wt = wo_t; N = 1024;
        n0 = (local % 16) * 64; k0 = (local / 16) * 64; perm = false;
    }
    {
        const int r = tid >> 2, c = (tid & 3) << 4;
        const float* src = W + (size_t)(k0 + r) * N + n0 + c;
        #pragma unroll
        for (int u = 0; u < 4; ++u)
            *(float4*)&ts[r][c + u * 4] = *(const float4*)&src[u * 4];
    }
    __syncthreads();
    {
        const int n = tid >> 2, kg = (tid & 3) << 4;
        f16x8 v0, v1;
        #pragma unroll
        for (int j = 0; j < 8; ++j) {
            v0[j] = (_Float16)ts[kg + j][n];
            v1[j] = (_Float16)ts[kg + 8 + j][n];
        }
        int ng = n0 + n;
        if (perm) {
            const int h = ng / 192, rr = ng % 192;
            ng = (rr >> 6) * 1024 + h * 64 + (rr & 63);   // sec-major
        }
        _Float16* dst = Wt + (size_t)ng * D_MODEL + k0 + kg;
        *(f16x8*)&dst[0] = v0;
        *(f16x8*)&dst[8] = v1;
    }
}

// ---------------- GEMM1: qkv with fused scatter epilogue ----------------
// A = x_h [4096][1024], Bt = wq_t [3072 permuted][1024]. 128x128 tile, BK=32.
__global__ __launch_bounds__(256) void gemm_qkv_kernel(
    const _Float16* __restrict__ A, const _Float16* __restrict__ Bt,
    const float* __restrict__ bias,
    _Float16* __restrict__ Qh, _Float16* __restrict__ Ksw, _Float16* __restrict__ Vsw)
{
    const int K = D_MODEL;
    __shared__ _Float16 lds[2][4096];
    const int tid = threadIdx.x;
    const int wave = tid >> 6, lane = tid & 63;
    const int quad = lane >> 4, l16 = lane & 15;
    const int m0 = blockIdx.y * 128, n0 = blockIdx.x * 128;
    const int wr = wave >> 1, wc = wave & 1;

    f32x4 acc[4][4] = {};

    const _Float16* gsrc = (wave < 2) ? (A + (size_t)m0 * K) : (Bt + (size_t)n0 * K);
    _Float16* ldst = (wave < 2) ? &lds[0][0] : &lds[1][0];
    const int sbase = (wave & 1) * 4;

    for (int k0 = 0; k0 < K; k0 += 32) {
        __syncthreads();
        #pragma unroll
        for (int j = 0; j < 4; ++j) {
            const int seg = sbase + j;
            const int chunk = seg >> 1;
            const int row = ((seg & 1) << 6) | lane;
            GLOBAL_LOAD_LDS16(gsrc + (size_t)row * K + k0 + chunk * 8, ldst + seg * 512);
        }
        __syncthreads();

        f16x8 a[4], b[4];
        #pragma unroll
        for (int mt = 0; mt < 4; ++mt)
            a[mt] = *(const f16x8*)&lds[0][quad * 1024 + (wr * 64 + mt * 16 + l16) * 8];
        #pragma unroll
        for (int nt = 0; nt < 4; ++nt)
            b[nt] = *(const f16x8*)&lds[1][quad * 1024 + (wc * 64 + nt * 16 + l16) * 8];
        #pragma unroll
        for (int mt = 0; mt < 4; ++mt)
            #pragma unroll
            for (int nt = 0; nt < 4; ++nt)
                acc[mt][nt] = __builtin_amdgcn_mfma_f32_16x16x32_f16(a[mt], b[nt], acc[mt][nt], 0, 0, 0);
    }

    // scatter epilogue; sec = c>>10 is block-uniform (1024 % 128 == 0)
    #pragma unroll
    for (int nt = 0; nt < 4; ++nt) {
        const int c = n0 + wc * 64 + nt * 16 + l16;
        const int sec = c >> 10, cc = c & 1023;
        const int h = cc >> 6, d = cc & 63;
        const float bv = bias[h * 192 + sec * 64 + d];
        #pragma unroll
        for (int mt = 0; mt < 4; ++mt) {
            #pragma unroll
            for (int r = 0; r < 4; ++r) {
                const int t = m0 + wr * 64 + mt * 16 + quad * 4 + r;
                const int bb = t >> 11, s = t & 2047;
                const float v = acc[mt][nt][r] + bv;
                if (sec == 0) {
                    Qh[(size_t)t * D_MODEL + cc] = (_Float16)(v * 0.1803368802f);
                } else if (sec == 1) {
                    Ksw[(((size_t)(bb * NHEAD + h) * 8 + (d >> 3)) * SEQ + s) * 8 + (d & 7)] = (_Float16)v;
                } else {
                    Vsw[(((size_t)(bb * NHEAD + h) * 256 + (s >> 3)) * HDIM + d) * 8 + (s & 7)] = (_Float16)v;
                }
            }
        }
    }
}

// ---------------- GEMM2: out = val @ Wout^T + bias (fp32 out) ----------------
__global__ __launch_bounds__(256) void gemm_out_kernel(
    const _Float16* __restrict__ A, const _Float16* __restrict__ Bt,
    const float* __restrict__ bias, float* __restrict__ Cout)
{
    const int K = D_MODEL, N = D_MODEL;
    __shared__ _Float16 lds[2][4096];
    const int tid = threadIdx.x;
    const int wave = tid >> 6, lane = tid & 63;
    const int quad = lane >> 4, l16 = lane & 15;
    const int m0 = blockIdx.y * 128, n0 = blockIdx.x * 128;
    const int wr = wave >> 1, wc = wave & 1;

    f32x4 acc[4][4] = {};

    const _Float16* gsrc = (wave < 2) ? (A + (size_t)m0 * K) : (Bt + (size_t)n0 * K);
    _Float16* ldst = (wave < 2) ? &lds[0][0] : &lds[1][0];
    const int sbase = (wave & 1) * 4;

    for (int k0 = 0; k0 < K; k0 += 32) {
        __syncthreads();
        #pragma unroll
        for (int j = 0; j < 4; ++j) {
            const int seg = sbase + j;
            const int chunk = seg >> 1;
            const int row = ((seg & 1) << 6) | lane;
            GLOBAL_LOAD_LDS16(gsrc + (size_t)row * K + k0 + chunk * 8, ldst + seg * 512);
        }
        __syncthreads();

        f16x8 a[4], b[4];
        #pragma unroll
        for (int mt = 0; mt < 4; ++mt)
            a[mt] = *(const f16x8*)&lds[0][quad * 1024 + (wr * 64 + mt * 16 + l16) * 8];
        #pragma unroll
        for (int nt = 0; nt < 4; ++nt)
            b[nt] = *(const f16x8*)&lds[1][quad * 1024 + (wc * 64 + nt * 16 + l16) * 8];
        #pragma unroll
        for (int mt = 0; mt < 4; ++mt)
            #pragma unroll
            for (int nt = 0; nt < 4; ++nt)
                acc[mt][nt] = __builtin_amdgcn_mfma_f32_16x16x32_f16(a[mt], b[nt], acc[mt][nt], 0, 0, 0);
    }

    #pragma unroll
    for (int nt = 0; nt < 4; ++nt) {
        const int col = n0 + wc * 64 + nt * 16 + l16;
        const float bv = bias[col];
        #pragma unroll
        for (int mt = 0; mt < 4; ++mt) {
            #pragma unroll
            for (int r = 0; r < 4; ++r) {
                const int row = m0 + wr * 64 + mt * 16 + quad * 4 + r;
                Cout[(size_t)row * N + col] = acc[mt][nt][r] + bv;
            }
        }
    }
}

// ---------------- fp16 MFMA flash attention (R5 math, Q pre-scaled) ----------------
__global__ __launch_bounds__(256) void attn_mfma_kernel(
    const _Float16* __restrict__ Qh,
    const _Float16* __restrict__ Ksw, const _Float16* __restrict__ Vsw,
    _Float16* __restrict__ val)
{
    __shared__ _Float16 Ks[8 * 64 * 8];     // [c=d/8][key 64][8]
    __shared__ _Float16 Vts[8 * 64 * 8];    // [cs=s/8][dim 64][8]
    __shared__ _Float16 Ps[64 * 72];        // [q 64][key 64 pad 72]

    const int tid = threadIdx.x;
    const int wave = tid >> 6, lane = tid & 63;
    const int quad = lane >> 4, l16 = lane & 15;
    const int qt = blockIdx.x, h = blockIdx.y, b = blockIdx.z;
    const int q0 = qt * 64;

    const size_t hsz = (size_t)8 * SEQ * 8;
    const _Float16* kh = Ksw + (size_t)(b * NHEAD + h) * hsz;
    const _Float16* vh = Vsw + (size_t)(b * NHEAD + h) * hsz;

    // Q B-fragment (already scaled by log2(e)/8 in GEMM1 epilogue)
    f16x8 qf[2];
    {
        const int row = q0 + wave * 16 + l16;
        const _Float16* src = Qh + (size_t)(b * SEQ + row) * D_MODEL + h * HDIM + quad * 8;
        qf[0] = *(const f16x8*)(src);
        qf[1] = *(const f16x8*)(src + 32);
    }

    f32x4 acc[4] = {};      // O[q=w*16+quad*4+r][d=nt*16+l16]
    float rs = 0.f;         // partial sum of p for q = w*16 + l16

    for (int kt = 0; kt < SEQ / 64; ++kt) {
        __syncthreads();
        #pragma unroll
        for (int jj = 0; jj < 2; ++jj) {
            const int c = wave * 2 + jj;
            GLOBAL_LOAD_LDS16(kh + ((size_t)c * SEQ + kt * 64 + lane) * 8, Ks + c * 512);
            GLOBAL_LOAD_LDS16(vh + ((size_t)(kt * 8 + c) * HDIM + lane) * 8, Vts + c * 512);
        }
        __syncthreads();

        // S^T = K Q^T
        f32x4 s[4] = {};
        #pragma unroll
        for (int mt = 0; mt < 4; ++mt) {
            const f16x8 kA0 = *(const f16x8*)&Ks[quad * 512 + (mt * 16 + l16) * 8];
            const f16x8 kA1 = *(const f16x8*)&Ks[(4 + quad) * 512 + (mt * 16 + l16) * 8];
            s[mt] = __builtin_amdgcn_mfma_f32_16x16x32_f16(kA0, qf[0], s[mt], 0, 0, 0);
            s[mt] = __builtin_amdgcn_mfma_f32_16x16x32_f16(kA1, qf[1], s[mt], 0, 0, 0);
        }

        // p = exp2(s); accumulate l; pack to P[q][key]
        #pragma unroll
        for (int mt = 0; mt < 4; ++mt) {
            const float p0 = __builtin_amdgcn_exp2f(s[mt][0]);
            const float p1 = __builtin_amdgcn_exp2f(s[mt][1]);
            const float p2 = __builtin_amdgcn_exp2f(s[mt][2]);
            const float p3 = __builtin_amdgcn_exp2f(s[mt][3]);
            rs += (p0 + p1) + (p2 + p3);
            uint2 w;
            w.x = __builtin_bit_cast(unsigned, __builtin_amdgcn_cvt_pkrtz(p0, p1));
            w.y = __builtin_bit_cast(unsigned, __builtin_amdgcn_cvt_pkrtz(p2, p3));
            *(uint2*)&Ps[(wave * 16 + l16) * 72 + mt * 16 + quad * 4] = w;
        }
        // intra-wave RAW on Ps: same-wave DS ordering, no barrier needed

        // O += P @ V
        const f16x8 pA0 = *(const f16x8*)&Ps[(wave * 16 + l16) * 72 + quad * 8];
        const f16x8 pA1 = *(const f16x8*)&Ps[(wave * 16 + l16) * 72 + 32 + quad * 8];
        #pragma unroll
        for (int nt = 0; nt < 4; ++nt) {
            const f16x8 v0 = *(const f16x8*)&Vts[quad * 512 + (nt * 16 + l16) * 8];
            const f16x8 v1 = *(const f16x8*)&Vts[(4 + quad) * 512 + (nt * 16 + l16) * 8];
            acc[nt] = __builtin_amdgcn_mfma_f32_16x16x32_f16(pA0, v0, acc[nt], 0, 0, 0);
            acc[nt] = __builtin_amdgcn_mfma_f32_16x16x32_f16(pA1, v1, acc[nt], 0, 0, 0);
        }
    }

    // l: reduce across quads; each l16 lane holds l for q=w*16+l16
    rs += __shfl_xor(rs, 16);
    rs += __shfl_xor(rs, 32);
    const float inv = 1.f / rs;
    float invr[4];
    #pragma unroll
    for (int r = 0; r < 4; ++r)
        invr[r] = __shfl(inv, quad * 4 + r, 16);

    #pragma unroll
    for (int r = 0; r < 4; ++r) {
        const int row = b * SEQ + q0 + wave * 16 + quad * 4 + r;
        #pragma unroll
        for (int nt = 0; nt < 4; ++nt) {
            const int col = h * HDIM + nt * 16 + l16;
            val[(size_t)row * D_MODEL + col] = (_Float16)(acc[nt][r] * invr[r]);
        }
    }
}

extern "C" void kernel_launch(void* const* d_in, const int* in_sizes, int n_in,
                              void* d_out, int out_size, void* d_ws, size_t ws_size,
                              hipStream_t stream)
{
    const float* x     = (const float*)d_in[0];
    const float* W_qkv = (const float*)d_in[1];
    const float* b_qkv = (const float*)d_in[2];
    const float* W_out = (const float*)d_in[3];
    const float* b_out = (const float*)d_in[4];

    char* ws = (char*)d_ws;
    _Float16* Qh    = (_Float16*)ws;                      // [4096][1024]      8 MiB
    _Float16* Ksw   = (_Float16*)(ws + (8u << 20));       // [32][8][2048][8]  8 MiB
    _Float16* Vsw   = (_Float16*)(ws + (16u << 20));      // [32][256][64][8]  8 MiB
    _Float16* val_h = (_Float16*)(ws + (24u << 20));      // [4096][1024]      8 MiB
    _Float16* wq_t  = (_Float16*)(ws + (32u << 20));      // [3072][1024]      6 MiB
    _Float16* wo_t  = (_Float16*)(ws + (38u << 20));      // [1024][1024]      2 MiB
    _Float16* x_h   = (_Float16*)(ws + (40u << 20));      // [4096][1024]      8 MiB

    prep_kernel<<<5120, 256, 0, stream>>>(x, x_h, W_qkv, wq_t, W_out, wo_t);
    gemm_qkv_kernel<<<dim3(3 * D_MODEL / 128, NTOK / 128), 256, 0, stream>>>(
        x_h, wq_t, b_qkv, Qh, Ksw, Vsw);
    attn_mfma_kernel<<<dim3(SEQ / 64, NHEAD, BATCH), 256, 0, stream>>>(Qh, Ksw, Vsw, val_h);
    gemm_out_kernel<<<dim3(D_MODEL / 128, NTOK / 128), 256, 0, stream>>>(
        val_h, wo_t, b_out, (float*)d_out);
}

// Round 8
// 247.661 us; speedup vs baseline: 1.0076x; 1.0076x over previous
//
#include <hip/hip_runtime.h>

// MultiHeadSelfAttention  B=2 S=2048 D=1024 H=16 d=64, fp32 in/out.
// R7: R5 dataflow (plain qkv epilogue + swizzle_kv + R5 attn) + merged prep,
//     with BK=64 GEMMs (32KB LDS, 16 iters x 32 MFMA) to halve barrier count.
//     Learned R6: wall = kernel-sum + ~86us FIXED harness overhead (launch-count
//     fusion is not a lever). Minimize kernel-sum.
// ws: Ksw 8M @0 | val_h 8M @8M | wq_t 6M @16M | wo_t 2M @22M | qkv 24M @24M
//     | x_h 8M @48M (dead after GEMM1, overwritten by Vsw)

#define D_MODEL 1024
#define NHEAD   16
#define HDIM    64
#define SEQ     2048
#define BATCH   2
#define NTOK    (BATCH * SEQ)

typedef float    f32x4 __attribute__((ext_vector_type(4)));
typedef _Float16 f16x8 __attribute__((ext_vector_type(8)));
typedef _Float16 f16x4 __attribute__((ext_vector_type(4)));

#define GLOBAL_LOAD_LDS16(gptr, lptr)                                            \
    __builtin_amdgcn_global_load_lds(                                            \
        (const __attribute__((address_space(1))) unsigned int*)(gptr),           \
        (__attribute__((address_space(3))) unsigned int*)(lptr), 16, 0, 0)

// ---------------- prep: x->fp16, W_qkv^T, W_out^T (one launch) ----------------
// blocks [0,4096): x convert; [4096,4864): W_qkv 64x64 tiles; [4864,5120): W_out
__global__ __launch_bounds__(256) void prep_kernel(
    const float* __restrict__ x, _Float16* __restrict__ xh,
    const float* __restrict__ Wqkv, _Float16* __restrict__ wq_t,
    const float* __restrict__ Wout, _Float16* __restrict__ wo_t)
{
    const int bx = blockIdx.x;
    const int tid = threadIdx.x;
    if (bx < 4096) {
        const int i = (bx * 256 + tid) * 4;
        const float4 v = *(const float4*)&x[i];
        f16x4 hh;
        hh[0] = (_Float16)v.x; hh[1] = (_Float16)v.y;
        hh[2] = (_Float16)v.z; hh[3] = (_Float16)v.w;
        *(f16x4*)&xh[i] = hh;
        return;
    }
    __shared__ float ts[64][65];
    const float* W; _Float16* Wt; int N, n0, k0;
    if (bx < 4096 + 768) {
        const int local = bx - 4096;
        W = Wqkv; Wt = wq_t; N = 3072;
        n0 = (local % 48) * 64; k0 = (local / 48) * 64;
    } else {
        const int local = bx - 4864;
        W = Wout; Wt = wo_t; N = 1024;
        n0 = (local % 16) * 64; k0 = (local / 16) * 64;
    }
    {
        const int r = tid >> 2, c = (tid & 3) << 4;
        const float* src = W + (size_t)(k0 + r) * N + n0 + c;
        #pragma unroll
        for (int u = 0; u < 4; ++u)
            *(float4*)&ts[r][c + u * 4] = *(const float4*)&src[u * 4];
    }
    __syncthreads();
    {
        const int n = tid >> 2, kg = (tid & 3) << 4;
        f16x8 v0, v1;
        #pragma unroll
        for (int j = 0; j < 8; ++j) {
            v0[j] = (_Float16)ts[kg + j][n];
            v1[j] = (_Float16)ts[kg + 8 + j][n];
        }
        _Float16* dst = Wt + (size_t)(n0 + n) * D_MODEL + k0 + kg;
        *(f16x8*)&dst[0] = v0;
        *(f16x8*)&dst[8] = v1;
    }
}

// ---------------- fp16 MFMA GEMM, BK=64: C[M][N] = A[M][K] @ (Bt[N][K])^T + bias ----------------
// 128x128 tile, 256 thr = 4 waves (2x2 of 64x64). Plane = [chunk(8)][row(128)][8 f16], 16KB.
// 16 K-iters, 32 MFMA + 1 barrier-pair each (half the barrier count of BK=32).
template<int OUT_F16>
__global__ __launch_bounds__(256) void gemm_f16_kernel(
    const _Float16* __restrict__ A, const _Float16* __restrict__ Bt,
    const float* __restrict__ bias, void* __restrict__ Cout,
    int M, int N, int K)
{
    __shared__ _Float16 lds[2][8192];     // 0=A plane, 1=B plane (16KB each)
    const int tid = threadIdx.x;
    const int wave = tid >> 6, lane = tid & 63;
    const int quad = lane >> 4, l16 = lane & 15;
    const int m0 = blockIdx.y * 128, n0 = blockIdx.x * 128;
    const int wr = wave >> 1, wc = wave & 1;

    f32x4 acc[4][4] = {};

    const _Float16* gsrc = (wave < 2) ? (A + (size_t)m0 * K) : (Bt + (size_t)n0 * K);
    _Float16* ldst = (wave < 2) ? &lds[0][0] : &lds[1][0];
    const int sbase = (wave & 1) * 8;            // 8 segments of 1KB per wave

    for (int k0 = 0; k0 < K; k0 += 64) {
        __syncthreads();
        #pragma unroll
        for (int j = 0; j < 8; ++j) {
            const int seg = sbase + j;
            const int chunk = seg >> 1;              // k-chunk 0..7
            const int row = ((seg & 1) << 6) | lane;
            GLOBAL_LOAD_LDS16(gsrc + (size_t)row * K + k0 + chunk * 8, ldst + seg * 512);
        }
        __syncthreads();

        #pragma unroll
        for (int kk = 0; kk < 2; ++kk) {
            f16x8 a[4], b[4];
            #pragma unroll
            for (int mt = 0; mt < 4; ++mt)
                a[mt] = *(const f16x8*)&lds[0][(kk * 4 + quad) * 1024 + (wr * 64 + mt * 16 + l16) * 8];
            #pragma unroll
            for (int nt = 0; nt < 4; ++nt)
                b[nt] = *(const f16x8*)&lds[1][(kk * 4 + quad) * 1024 + (wc * 64 + nt * 16 + l16) * 8];
            #pragma unroll
            for (int mt = 0; mt < 4; ++mt)
                #pragma unroll
                for (int nt = 0; nt < 4; ++nt)
                    acc[mt][nt] = __builtin_amdgcn_mfma_f32_16x16x32_f16(a[mt], b[nt], acc[mt][nt], 0, 0, 0);
        }
    }

    #pragma unroll
    for (int nt = 0; nt < 4; ++nt) {
        const int col = n0 + wc * 64 + nt * 16 + l16;
        const float bv = bias[col];
        #pragma unroll
        for (int mt = 0; mt < 4; ++mt) {
            #pragma unroll
            for (int r = 0; r < 4; ++r) {
                const int row = m0 + wr * 64 + mt * 16 + quad * 4 + r;
                const float v = acc[mt][nt][r] + bv;
                if (OUT_F16) ((_Float16*)Cout)[(size_t)row * N + col] = (_Float16)v;
                else         ((float*)Cout)[(size_t)row * N + col] = v;
            }
        }
    }
}

// ---------------- K,V slices of qkv -> swizzled MFMA-ready layouts ----------------
// Ksw[b,h][c=d>>3][s][j=d&7]   Vsw[b,h][cs=s>>3][d][j=s&7]
__global__ __launch_bounds__(256) void swizzle_kv_kernel(
    const _Float16* __restrict__ qkv,
    _Float16* __restrict__ Ksw, _Float16* __restrict__ Vsw)
{
    __shared__ _Float16 ts[64][72];
    const int tid = threadIdx.x;
    const int s0 = blockIdx.x * 64, h = blockIdx.y, b = blockIdx.z;
    const size_t hsz = (size_t)8 * SEQ * 8;
    _Float16* kh = Ksw + (size_t)(b * NHEAD + h) * hsz;
    _Float16* vh = Vsw + (size_t)(b * NHEAD + h) * hsz;

    {
        const int s = s0 + (tid >> 2);
        const int dg = (tid & 3) << 4;
        const _Float16* src = qkv + (size_t)(b * SEQ + s) * (3 * D_MODEL) + h * (3 * HDIM) + HDIM + dg;
        const f16x8 v0 = *(const f16x8*)&src[0];
        const f16x8 v1 = *(const f16x8*)&src[8];
        const int c0 = dg >> 3;
        *(f16x8*)&kh[((size_t)c0 * SEQ + s) * 8]       = v0;
        *(f16x8*)&kh[((size_t)(c0 + 1) * SEQ + s) * 8] = v1;
    }
    {
        const int s = tid >> 2, dg = (tid & 3) << 4;
        const _Float16* src = qkv + (size_t)(b * SEQ + s0 + s) * (3 * D_MODEL) + h * (3 * HDIM) + 2 * HDIM + dg;
        *(f16x8*)&ts[s][dg]     = *(const f16x8*)&src[0];
        *(f16x8*)&ts[s][dg + 8] = *(const f16x8*)&src[8];
    }
    __syncthreads();
    {
        const int d = tid >> 2, sg = (tid & 3) << 4;
        f16x8 v0, v1;
        #pragma unroll
        for (int j = 0; j < 8; ++j) { v0[j] = ts[sg + j][d]; v1[j] = ts[sg + 8 + j][d]; }
        const int cs0 = (s0 + sg) >> 3;
        *(f16x8*)&vh[((size_t)cs0 * HDIM + d) * 8]       = v0;
        *(f16x8*)&vh[((size_t)(cs0 + 1) * HDIM + d) * 8] = v1;
    }
}

// ---------------- fp16 MFMA flash attention (R5: max-free exp2, S^T tiles) ----------------
__global__ __launch_bounds__(256) void attn_mfma_kernel(
    const _Float16* __restrict__ qkv,
    const _Float16* __restrict__ Ksw, const _Float16* __restrict__ Vsw,
    _Float16* __restrict__ val)
{
    __shared__ _Float16 Ks[8 * 64 * 8];
    __shared__ _Float16 Vts[8 * 64 * 8];
    __shared__ _Float16 Ps[64 * 72];

    const int tid = threadIdx.x;
    const int wave = tid >> 6, lane = tid & 63;
    const int quad = lane >> 4, l16 = lane & 15;
    const int qt = blockIdx.x, h = blockIdx.y, b = blockIdx.z;
    const int q0 = qt * 64;

    const size_t hsz = (size_t)8 * SEQ * 8;
    const _Float16* kh = Ksw + (size_t)(b * NHEAD + h) * hsz;
    const _Float16* vh = Vsw + (size_t)(b * NHEAD + h) * hsz;

    f16x8 qf[2];
    {
        const int row = q0 + wave * 16 + l16;
        const _Float16* src = qkv + (size_t)(b * SEQ + row) * (3 * D_MODEL) + h * (3 * HDIM) + quad * 8;
        const f16x8 t0 = *(const f16x8*)(src);
        const f16x8 t1 = *(const f16x8*)(src + 32);
        #pragma unroll
        for (int j = 0; j < 8; ++j) {
            qf[0][j] = (_Float16)((float)t0[j] * 0.1803368802f);
            qf[1][j] = (_Float16)((float)t1[j] * 0.1803368802f);
        }
    }

    f32x4 acc[4] = {};
    float rs = 0.f;

    for (int kt = 0; kt < SEQ / 64; ++kt) {
        __syncthreads();
        #pragma unroll
        for (int jj = 0; jj < 2; ++jj) {
            const int c = wave * 2 + jj;
            GLOBAL_LOAD_LDS16(kh + ((size_t)c * SEQ + kt * 64 + lane) * 8, Ks + c * 512);
            GLOBAL_LOAD_LDS16(vh + ((size_t)(kt * 8 + c) * HDIM + lane) * 8, Vts + c * 512);
        }
        __syncthreads();

        f32x4 s[4] = {};
        #pragma unroll
        for (int mt = 0; mt < 4; ++mt) {
            const f16x8 kA0 = *(const f16x8*)&Ks[quad * 512 + (mt * 16 + l16) * 8];
            const f16x8 kA1 = *(const f16x8*)&Ks[(4 + quad) * 512 + (mt * 16 + l16) * 8];
            s[mt] = __builtin_amdgcn_mfma_f32_16x16x32_f16(kA0, qf[0], s[mt], 0, 0, 0);
            s[mt] = __builtin_amdgcn_mfma_f32_16x16x32_f16(kA1, qf[1], s[mt], 0, 0, 0);
        }

        #pragma unroll
        for (int mt = 0; mt < 4; ++mt) {
            const float p0 = __builtin_amdgcn_exp2f(s[mt][0]);
            const float p1 = __builtin_amdgcn_exp2f(s[mt][1]);
            const float p2 = __builtin_amdgcn_exp2f(s[mt][2]);
            const float p3 = __builtin_amdgcn_exp2f(s[mt][3]);
            rs += (p0 + p1) + (p2 + p3);
            uint2 w;
            w.x = __builtin_bit_cast(unsigned, __builtin_amdgcn_cvt_pkrtz(p0, p1));
            w.y = __builtin_bit_cast(unsigned, __builtin_amdgcn_cvt_pkrtz(p2, p3));
            *(uint2*)&Ps[(wave * 16 + l16) * 72 + mt * 16 + quad * 4] = w;
        }

        const f16x8 pA0 = *(const f16x8*)&Ps[(wave * 16 + l16) * 72 + quad * 8];
        const f16x8 pA1 = *(const f16x8*)&Ps[(wave * 16 + l16) * 72 + 32 + quad * 8];
        #pragma unroll
        for (int nt = 0; nt < 4; ++nt) {
            const f16x8 v0 = *(const f16x8*)&Vts[quad * 512 + (nt * 16 + l16) * 8];
            const f16x8 v1 = *(const f16x8*)&Vts[(4 + quad) * 512 + (nt * 16 + l16) * 8];
            acc[nt] = __builtin_amdgcn_mfma_f32_16x16x32_f16(pA0, v0, acc[nt], 0, 0, 0);
            acc[nt] = __builtin_amdgcn_mfma_f32_16x16x32_f16(pA1, v1, acc[nt], 0, 0, 0);
        }
    }

    rs += __shfl_xor(rs, 16);
    rs += __shfl_xor(rs, 32);
    const float inv = 1.f / rs;
    float invr[4];
    #pragma unroll
    for (int r = 0; r < 4; ++r)
        invr[r] = __shfl(inv, quad * 4 + r, 16);

    #pragma unroll
    for (int r = 0; r < 4; ++r) {
        const int row = b * SEQ + q0 + wave * 16 + quad * 4 + r;
        #pragma unroll
        for (int nt = 0; nt < 4; ++nt) {
            const int col = h * HDIM + nt * 16 + l16;
            val[(size_t)row * D_MODEL + col] = (_Float16)(acc[nt][r] * invr[r]);
        }
    }
}

extern "C" void kernel_launch(void* const* d_in, const int* in_sizes, int n_in,
                              void* d_out, int out_size, void* d_ws, size_t ws_size,
                              hipStream_t stream)
{
    const float* x     = (const float*)d_in[0];
    const float* W_qkv = (const float*)d_in[1];
    const float* b_qkv = (const float*)d_in[2];
    const float* W_out = (const float*)d_in[3];
    const float* b_out = (const float*)d_in[4];

    char* ws = (char*)d_ws;
    _Float16* Ksw   = (_Float16*)ws;                      // [32][8][2048][8]  8 MiB
    _Float16* val_h = (_Float16*)(ws + (8u << 20));       // [4096][1024]      8 MiB
    _Float16* wq_t  = (_Float16*)(ws + (16u << 20));      // [3072][1024]      6 MiB
    _Float16* wo_t  = (_Float16*)(ws + (22u << 20));      // [1024][1024]      2 MiB
    _Float16* qkv_h = (_Float16*)(ws + (24u << 20));      // [4096][3072]     24 MiB
    _Float16* x_h   = (_Float16*)(ws + (48u << 20));      // [4096][1024]      8 MiB
    _Float16* Vsw   = (_Float16*)(ws + (48u << 20));      // overwrites dead x_h

    prep_kernel<<<5120, 256, 0, stream>>>(x, x_h, W_qkv, wq_t, W_out, wo_t);
    gemm_f16_kernel<1><<<dim3(3 * D_MODEL / 128, NTOK / 128), 256, 0, stream>>>(
        x_h, wq_t, b_qkv, qkv_h, NTOK, 3 * D_MODEL, D_MODEL);
    swizzle_kv_kernel<<<dim3(SEQ / 64, NHEAD, BATCH), 256, 0, stream>>>(qkv_h, Ksw, Vsw);
    attn_mfma_kernel<<<dim3(SEQ / 64, NHEAD, BATCH), 256, 0, stream>>>(qkv_h, Ksw, Vsw, val_h);
    gemm_f16_kernel<0><<<dim3(D_MODEL / 128, NTOK / 128), 256, 0, stream>>>(
        val_h, wo_t, b_out, d_out, NTOK, D_MODEL, D_MODEL);
}

// Round 9
// 226.809 us; speedup vs baseline: 1.1002x; 1.0919x over previous
//
#include <hip/hip_runtime.h>

// MultiHeadSelfAttention  B=2 S=2048 D=1024 H=16 d=64, fp32 in/out.
// R8: BK=32 (BK=64 regressed, R7) + 8-wave 512-thread GEMM blocks for TLP.
//   gemm1: 128x128 tile, 8 waves of 32x64 -> 24 waves/CU possible (vs 12).
//   gemm2: 128x64 tile, 512 blocks (was 256 = 1/CU, no overlap), 8 waves of 32x32.
//   attn/prep/swizzle unchanged from R7 (R5 math).
// Learned R6: wall = kernel-sum + ~86us fixed overhead; minimize kernel-sum.
// ws: Ksw 8M @0 | val_h 8M @8M | wq_t 6M @16M | wo_t 2M @22M | qkv 24M @24M
//     | x_h 8M @48M (dead after GEMM1, overwritten by Vsw)

#define D_MODEL 1024
#define NHEAD   16
#define HDIM    64
#define SEQ     2048
#define BATCH   2
#define NTOK    (BATCH * SEQ)

typedef float    f32x4 __attribute__((ext_vector_type(4)));
typedef _Float16 f16x8 __attribute__((ext_vector_type(8)));
typedef _Float16 f16x4 __attribute__((ext_vector_type(4)));

#define GLOBAL_LOAD_LDS16(gptr, lptr)                                            \
    __builtin_amdgcn_global_load_lds(                                            \
        (const __attribute__((address_space(1))) unsigned int*)(gptr),           \
        (__attribute__((address_space(3))) unsigned int*)(lptr), 16, 0, 0)

// ---------------- prep: x->fp16, W_qkv^T, W_out^T (one launch) ----------------
__global__ __launch_bounds__(256) void prep_kernel(
    const float* __restrict__ x, _Float16* __restrict__ xh,
    const float* __restrict__ Wqkv, _Float16* __restrict__ wq_t,
    const float* __restrict__ Wout, _Float16* __restrict__ wo_t)
{
    const int bx = blockIdx.x;
    const int tid = threadIdx.x;
    if (bx < 4096) {
        const int i = (bx * 256 + tid) * 4;
        const float4 v = *(const float4*)&x[i];
        f16x4 hh;
        hh[0] = (_Float16)v.x; hh[1] = (_Float16)v.y;
        hh[2] = (_Float16)v.z; hh[3] = (_Float16)v.w;
        *(f16x4*)&xh[i] = hh;
        return;
    }
    __shared__ float ts[64][65];
    const float* W; _Float16* Wt; int N, n0, k0;
    if (bx < 4096 + 768) {
        const int local = bx - 4096;
        W = Wqkv; Wt = wq_t; N = 3072;
        n0 = (local % 48) * 64; k0 = (local / 48) * 64;
    } else {
        const int local = bx - 4864;
        W = Wout; Wt = wo_t; N = 1024;
        n0 = (local % 16) * 64; k0 = (local / 16) * 64;
    }
    {
        const int r = tid >> 2, c = (tid & 3) << 4;
        const float* src = W + (size_t)(k0 + r) * N + n0 + c;
        #pragma unroll
        for (int u = 0; u < 4; ++u)
            *(float4*)&ts[r][c + u * 4] = *(const float4*)&src[u * 4];
    }
    __syncthreads();
    {
        const int n = tid >> 2, kg = (tid & 3) << 4;
        f16x8 v0, v1;
        #pragma unroll
        for (int j = 0; j < 8; ++j) {
            v0[j] = (_Float16)ts[kg + j][n];
            v1[j] = (_Float16)ts[kg + 8 + j][n];
        }
        _Float16* dst = Wt + (size_t)(n0 + n) * D_MODEL + k0 + kg;
        *(f16x8*)&dst[0] = v0;
        *(f16x8*)&dst[8] = v1;
    }
}

// ---------------- GEMM1: 128x128 tile, BK=32, 512 threads (8 waves of 32x64) ----------------
__global__ __launch_bounds__(512) void gemm_qkv_kernel(
    const _Float16* __restrict__ A, const _Float16* __restrict__ Bt,
    const float* __restrict__ bias, _Float16* __restrict__ Cout,
    int M, int N, int K)
{
    __shared__ _Float16 lds[2][4096];     // A plane 8KB, B plane 8KB: [chunk4][row128][8]
    const int tid = threadIdx.x;
    const int wave = tid >> 6, lane = tid & 63;
    const int quad = lane >> 4, l16 = lane & 15;
    const int m0 = blockIdx.y * 128, n0 = blockIdx.x * 128;
    const int wr = wave >> 1, wc = wave & 1;       // wave tile: rows wr*32, cols wc*64

    f32x4 acc[2][4] = {};

    const bool isA = wave < 4;
    const _Float16* gsrc = isA ? (A + (size_t)m0 * K) : (Bt + (size_t)n0 * K);
    _Float16* ldst = isA ? &lds[0][0] : &lds[1][0];
    const int sbase = (wave & 3) * 2;              // 2 segments of 1KB per wave

    for (int k0 = 0; k0 < K; k0 += 32) {
        __syncthreads();
        #pragma unroll
        for (int j = 0; j < 2; ++j) {
            const int seg = sbase + j;
            const int chunk = seg >> 1;
            const int row = ((seg & 1) << 6) | lane;
            GLOBAL_LOAD_LDS16(gsrc + (size_t)row * K + k0 + chunk * 8, ldst + seg * 512);
        }
        __syncthreads();

        f16x8 a[2], b[4];
        #pragma unroll
        for (int mt = 0; mt < 2; ++mt)
            a[mt] = *(const f16x8*)&lds[0][quad * 1024 + (wr * 32 + mt * 16 + l16) * 8];
        #pragma unroll
        for (int nt = 0; nt < 4; ++nt)
            b[nt] = *(const f16x8*)&lds[1][quad * 1024 + (wc * 64 + nt * 16 + l16) * 8];
        #pragma unroll
        for (int mt = 0; mt < 2; ++mt)
            #pragma unroll
            for (int nt = 0; nt < 4; ++nt)
                acc[mt][nt] = __builtin_amdgcn_mfma_f32_16x16x32_f16(a[mt], b[nt], acc[mt][nt], 0, 0, 0);
    }

    #pragma unroll
    for (int nt = 0; nt < 4; ++nt) {
        const int col = n0 + wc * 64 + nt * 16 + l16;
        const float bv = bias[col];
        #pragma unroll
        for (int mt = 0; mt < 2; ++mt) {
            #pragma unroll
            for (int r = 0; r < 4; ++r) {
                const int row = m0 + wr * 32 + mt * 16 + quad * 4 + r;
                Cout[(size_t)row * N + col] = (_Float16)(acc[mt][nt][r] + bv);
            }
        }
    }
}

// ---------------- GEMM2: 128x64 tile, BK=32, 512 threads (8 waves of 32x32), fp32 out ----------------
__global__ __launch_bounds__(512) void gemm_out_kernel(
    const _Float16* __restrict__ A, const _Float16* __restrict__ Bt,
    const float* __restrict__ bias, float* __restrict__ Cout)
{
    const int K = D_MODEL, N = D_MODEL;
    __shared__ _Float16 ldsA[4096];       // [chunk4][row128][8] 8KB
    __shared__ _Float16 ldsB[2048];       // [chunk4][row64][8]  4KB
    const int tid = threadIdx.x;
    const int wave = tid >> 6, lane = tid & 63;
    const int quad = lane >> 4, l16 = lane & 15;
    const int m0 = blockIdx.y * 128, n0 = blockIdx.x * 64;
    const int wr = wave >> 1, wc = wave & 1;       // wave tile: rows wr*32, cols wc*32

    f32x4 acc[2][2] = {};

    for (int k0 = 0; k0 < K; k0 += 32) {
        __syncthreads();
        if (wave < 4) {
            #pragma unroll
            for (int j = 0; j < 2; ++j) {
                const int seg = wave * 2 + j;          // 0..7
                const int chunk = seg >> 1;
                const int row = ((seg & 1) << 6) | lane;
                GLOBAL_LOAD_LDS16(A + (size_t)(m0 + row) * K + k0 + chunk * 8, ldsA + seg * 512);
            }
        } else {
            const int seg = wave - 4;                  // 0..3 (chunk = seg, 64 rows)
            GLOBAL_LOAD_LDS16(Bt + (size_t)(n0 + lane) * K + k0 + seg * 8, ldsB + seg * 512);
        }
        __syncthreads();

        f16x8 a[2], b[2];
        #pragma unroll
        for (int mt = 0; mt < 2; ++mt)
            a[mt] = *(const f16x8*)&ldsA[quad * 1024 + (wr * 32 + mt * 16 + l16) * 8];
        #pragma unroll
        for (int nt = 0; nt < 2; ++nt)
            b[nt] = *(const f16x8*)&ldsB[quad * 512 + (wc * 32 + nt * 16 + l16) * 8];
        #pragma unroll
        for (int mt = 0; mt < 2; ++mt)
            #pragma unroll
            for (int nt = 0; nt < 2; ++nt)
                acc[mt][nt] = __builtin_amdgcn_mfma_f32_16x16x32_f16(a[mt], b[nt], acc[mt][nt], 0, 0, 0);
    }

    #pragma unroll
    for (int nt = 0; nt < 2; ++nt) {
        const int col = n0 + wc * 32 + nt * 16 + l16;
        const float bv = bias[col];
        #pragma unroll
        for (int mt = 0; mt < 2; ++mt) {
            #pragma unroll
            for (int r = 0; r < 4; ++r) {
                const int row = m0 + wr * 32 + mt * 16 + quad * 4 + r;
                Cout[(size_t)row * N + col] = acc[mt][nt][r] + bv;
            }
        }
    }
}

// ---------------- K,V slices of qkv -> swizzled MFMA-ready layouts ----------------
__global__ __launch_bounds__(256) void swizzle_kv_kernel(
    const _Float16* __restrict__ qkv,
    _Float16* __restrict__ Ksw, _Float16* __restrict__ Vsw)
{
    __shared__ _Float16 ts[64][72];
    const int tid = threadIdx.x;
    const int s0 = blockIdx.x * 64, h = blockIdx.y, b = blockIdx.z;
    const size_t hsz = (size_t)8 * SEQ * 8;
    _Float16* kh = Ksw + (size_t)(b * NHEAD + h) * hsz;
    _Float16* vh = Vsw + (size_t)(b * NHEAD + h) * hsz;

    {
        const int s = s0 + (tid >> 2);
        const int dg = (tid & 3) << 4;
        const _Float16* src = qkv + (size_t)(b * SEQ + s) * (3 * D_MODEL) + h * (3 * HDIM) + HDIM + dg;
        const f16x8 v0 = *(const f16x8*)&src[0];
        const f16x8 v1 = *(const f16x8*)&src[8];
        const int c0 = dg >> 3;
        *(f16x8*)&kh[((size_t)c0 * SEQ + s) * 8]       = v0;
        *(f16x8*)&kh[((size_t)(c0 + 1) * SEQ + s) * 8] = v1;
    }
    {
        const int s = tid >> 2, dg = (tid & 3) << 4;
        const _Float16* src = qkv + (size_t)(b * SEQ + s0 + s) * (3 * D_MODEL) + h * (3 * HDIM) + 2 * HDIM + dg;
        *(f16x8*)&ts[s][dg]     = *(const f16x8*)&src[0];
        *(f16x8*)&ts[s][dg + 8] = *(const f16x8*)&src[8];
    }
    __syncthreads();
    {
        const int d = tid >> 2, sg = (tid & 3) << 4;
        f16x8 v0, v1;
        #pragma unroll
        for (int j = 0; j < 8; ++j) { v0[j] = ts[sg + j][d]; v1[j] = ts[sg + 8 + j][d]; }
        const int cs0 = (s0 + sg) >> 3;
        *(f16x8*)&vh[((size_t)cs0 * HDIM + d) * 8]       = v0;
        *(f16x8*)&vh[((size_t)(cs0 + 1) * HDIM + d) * 8] = v1;
    }
}

// ---------------- fp16 MFMA flash attention (R5: max-free exp2, S^T tiles) ----------------
__global__ __launch_bounds__(256) void attn_mfma_kernel(
    const _Float16* __restrict__ qkv,
    const _Float16* __restrict__ Ksw, const _Float16* __restrict__ Vsw,
    _Float16* __restrict__ val)
{
    __shared__ _Float16 Ks[8 * 64 * 8];
    __shared__ _Float16 Vts[8 * 64 * 8];
    __shared__ _Float16 Ps[64 * 72];

    const int tid = threadIdx.x;
    const int wave = tid >> 6, lane = tid & 63;
    const int quad = lane >> 4, l16 = lane & 15;
    const int qt = blockIdx.x, h = blockIdx.y, b = blockIdx.z;
    const int q0 = qt * 64;

    const size_t hsz = (size_t)8 * SEQ * 8;
    const _Float16* kh = Ksw + (size_t)(b * NHEAD + h) * hsz;
    const _Float16* vh = Vsw + (size_t)(b * NHEAD + h) * hsz;

    f16x8 qf[2];
    {
        const int row = q0 + wave * 16 + l16;
        const _Float16* src = qkv + (size_t)(b * SEQ + row) * (3 * D_MODEL) + h * (3 * HDIM) + quad * 8;
        const f16x8 t0 = *(const f16x8*)(src);
        const f16x8 t1 = *(const f16x8*)(src + 32);
        #pragma unroll
        for (int j = 0; j < 8; ++j) {
            qf[0][j] = (_Float16)((float)t0[j] * 0.1803368802f);
            qf[1][j] = (_Float16)((float)t1[j] * 0.1803368802f);
        }
    }

    f32x4 acc[4] = {};
    float rs = 0.f;

    for (int kt = 0; kt < SEQ / 64; ++kt) {
        __syncthreads();
        #pragma unroll
        for (int jj = 0; jj < 2; ++jj) {
            const int c = wave * 2 + jj;
            GLOBAL_LOAD_LDS16(kh + ((size_t)c * SEQ + kt * 64 + lane) * 8, Ks + c * 512);
            GLOBAL_LOAD_LDS16(vh + ((size_t)(kt * 8 + c) * HDIM + lane) * 8, Vts + c * 512);
        }
        __syncthreads();

        f32x4 s[4] = {};
        #pragma unroll
        for (int mt = 0; mt < 4; ++mt) {
            const f16x8 kA0 = *(const f16x8*)&Ks[quad * 512 + (mt * 16 + l16) * 8];
            const f16x8 kA1 = *(const f16x8*)&Ks[(4 + quad) * 512 + (mt * 16 + l16) * 8];
            s[mt] = __builtin_amdgcn_mfma_f32_16x16x32_f16(kA0, qf[0], s[mt], 0, 0, 0);
            s[mt] = __builtin_amdgcn_mfma_f32_16x16x32_f16(kA1, qf[1], s[mt], 0, 0, 0);
        }

        #pragma unroll
        for (int mt = 0; mt < 4; ++mt) {
            const float p0 = __builtin_amdgcn_exp2f(s[mt][0]);
            const float p1 = __builtin_amdgcn_exp2f(s[mt][1]);
            const float p2 = __builtin_amdgcn_exp2f(s[mt][2]);
            const float p3 = __builtin_amdgcn_exp2f(s[mt][3]);
            rs += (p0 + p1) + (p2 + p3);
            uint2 w;
            w.x = __builtin_bit_cast(unsigned, __builtin_amdgcn_cvt_pkrtz(p0, p1));
            w.y = __builtin_bit_cast(unsigned, __builtin_amdgcn_cvt_pkrtz(p2, p3));
            *(uint2*)&Ps[(wave * 16 + l16) * 72 + mt * 16 + quad * 4] = w;
        }

        const f16x8 pA0 = *(const f16x8*)&Ps[(wave * 16 + l16) * 72 + quad * 8];
        const f16x8 pA1 = *(const f16x8*)&Ps[(wave * 16 + l16) * 72 + 32 + quad * 8];
        #pragma unroll
        for (int nt = 0; nt < 4; ++nt) {
            const f16x8 v0 = *(const f16x8*)&Vts[quad * 512 + (nt * 16 + l16) * 8];
            const f16x8 v1 = *(const f16x8*)&Vts[(4 + quad) * 512 + (nt * 16 + l16) * 8];
            acc[nt] = __builtin_amdgcn_mfma_f32_16x16x32_f16(pA0, v0, acc[nt], 0, 0, 0);
            acc[nt] = __builtin_amdgcn_mfma_f32_16x16x32_f16(pA1, v1, acc[nt], 0, 0, 0);
        }
    }

    rs += __shfl_xor(rs, 16);
    rs += __shfl_xor(rs, 32);
    const float inv = 1.f / rs;
    float invr[4];
    #pragma unroll
    for (int r = 0; r < 4; ++r)
        invr[r] = __shfl(inv, quad * 4 + r, 16);

    #pragma unroll
    for (int r = 0; r < 4; ++r) {
        const int row = b * SEQ + q0 + wave * 16 + quad * 4 + r;
        #pragma unroll
        for (int nt = 0; nt < 4; ++nt) {
            const int col = h * HDIM + nt * 16 + l16;
            val[(size_t)row * D_MODEL + col] = (_Float16)(acc[nt][r] * invr[r]);
        }
    }
}

extern "C" void kernel_launch(void* const* d_in, const int* in_sizes, int n_in,
                              void* d_out, int out_size, void* d_ws, size_t ws_size,
                              hipStream_t stream)
{
    const float* x     = (const float*)d_in[0];
    const float* W_qkv = (const float*)d_in[1];
    const float* b_qkv = (const float*)d_in[2];
    const float* W_out = (const float*)d_in[3];
    const float* b_out = (const float*)d_in[4];

    char* ws = (char*)d_ws;
    _Float16* Ksw   = (_Float16*)ws;                      // [32][8][2048][8]  8 MiB
    _Float16* val_h = (_Float16*)(ws + (8u << 20));       // [4096][1024]      8 MiB
    _Float16* wq_t  = (_Float16*)(ws + (16u << 20));      // [3072][1024]      6 MiB
    _Float16* wo_t  = (_Float16*)(ws + (22u << 20));      // [1024][1024]      2 MiB
    _Float16* qkv_h = (_Float16*)(ws + (24u << 20));      // [4096][3072]     24 MiB
    _Float16* x_h   = (_Float16*)(ws + (48u << 20));      // [4096][1024]      8 MiB
    _Float16* Vsw   = (_Float16*)(ws + (48u << 20));      // overwrites dead x_h

    prep_kernel<<<5120, 256, 0, stream>>>(x, x_h, W_qkv, wq_t, W_out, wo_t);
    gemm_qkv_kernel<<<dim3(3 * D_MODEL / 128, NTOK / 128), 512, 0, stream>>>(
        x_h, wq_t, b_qkv, qkv_h, NTOK, 3 * D_MODEL, D_MODEL);
    swizzle_kv_kernel<<<dim3(SEQ / 64, NHEAD, BATCH), 256, 0, stream>>>(qkv_h, Ksw, Vsw);
    attn_mfma_kernel<<<dim3(SEQ / 64, NHEAD, BATCH), 256, 0, stream>>>(qkv_h, Ksw, Vsw, val_h);
    gemm_out_kernel<<<dim3(D_MODEL / 64, NTOK / 128), 512, 0, stream>>>(
        val_h, wo_t, b_out, (float*)d_out);
}